// Round 11
// baseline (231.210 us; speedup 1.0000x reference)
//
#include <hip/hip_runtime.h>

// XL-attention: out = (softmax(Qh Kh^T / 8) Vh) @ Wc^T + bc
// L=2048, B=2, M=2048 -> J=4096, D=1024, H=16, Dh=64.
// All matmuls in bf16 MFMA (16x16x32), f32 accumulate.
// Attention: swapped QK^T (S^T = K Q^T), in-register defer-max softmax,
// in-register P. 4-wave blocks, 32 q-rows/wave (M=2), grid 512 = 2 blocks/CU.
// K is read GLOBAL->REGISTER (L2-served, rotating 2-subtile reg buffers,
// compiler-scheduled prefetch) -- halves LDS port traffic, the measured
// bottleneck. V staged in LDS (pre-permuted so PV B-frag is one
// ds_read_b128), double-buffered pairs, unrolled, setprio.

using short8 = __attribute__((ext_vector_type(8))) short;
using f32x4  = __attribute__((ext_vector_type(4))) float;

#define DEV __device__ __forceinline__

DEV unsigned short f2bf(float f) {
  union { float f; unsigned int u; } x; x.f = f;
  unsigned int r = x.u + 0x7FFFu + ((x.u >> 16) & 1u);
  return (unsigned short)(r >> 16);
}

DEV unsigned int cvtpk(float lo, float hi) {
  unsigned int r;
  asm("v_cvt_pk_bf16_f32 %0, %1, %2" : "=v"(r) : "v"(lo), "v"(hi));
  return r;
}

DEV float max3f(float a, float b, float c) {
  float d;
  asm("v_max3_f32 %0, %1, %2, %3" : "=v"(d) : "v"(a), "v"(b), "v"(c));
  return d;
}

DEV void gload_lds16(const unsigned short* g, unsigned short* l) {
  __builtin_amdgcn_global_load_lds(
      (const __attribute__((address_space(1))) unsigned int*)g,
      (__attribute__((address_space(3))) unsigned int*)l, 16, 0, 0);
}

#define BARRIER_RAW()                      \
  do {                                     \
    __builtin_amdgcn_sched_barrier(0);     \
    __builtin_amdgcn_s_barrier();          \
    __builtin_amdgcn_sched_barrier(0);     \
  } while (0)

// ---------------------------------------------------------------------------
// f32 -> bf16 conversion of all inputs (q, concat(mem,kv), 4 weights)
__global__ __launch_bounds__(256) void convert_all(
    const float* __restrict__ q, const float* __restrict__ mem_,
    const float* __restrict__ kv, const float* __restrict__ wq,
    const float* __restrict__ wk, const float* __restrict__ wv,
    const float* __restrict__ wc, unsigned short* __restrict__ a_bf,
    unsigned short* __restrict__ c_bf, unsigned short* __restrict__ w_bf) {
  size_t u = (size_t)blockIdx.x * 256 + threadIdx.x;
  const float* src;
  unsigned short* dst;
  if (u < 524288u)        { src = q    + u * 8;                dst = a_bf + u * 8; }
  else if (u < 1048576u)  { src = mem_ + (u - 524288u) * 8;    dst = c_bf + (u - 524288u) * 8; }
  else if (u < 1572864u)  { src = kv   + (u - 1048576u) * 8;   dst = c_bf + 4194304u + (u - 1048576u) * 8; }
  else if (u < 1703936u)  { src = wq   + (u - 1572864u) * 8;   dst = w_bf + (u - 1572864u) * 8; }
  else if (u < 1835008u)  { src = wk   + (u - 1703936u) * 8;   dst = w_bf + 1048576u + (u - 1703936u) * 8; }
  else if (u < 1966080u)  { src = wv   + (u - 1835008u) * 8;   dst = w_bf + 2097152u + (u - 1835008u) * 8; }
  else                    { src = wc   + (u - 1966080u) * 8;   dst = w_bf + 3145728u + (u - 1966080u) * 8; }
  float4 v0 = ((const float4*)src)[0];
  float4 v1 = ((const float4*)src)[1];
  union { unsigned short us[8]; uint4 v; } o;
  o.us[0] = f2bf(v0.x); o.us[1] = f2bf(v0.y); o.us[2] = f2bf(v0.z); o.us[3] = f2bf(v0.w);
  o.us[4] = f2bf(v1.x); o.us[5] = f2bf(v1.y); o.us[6] = f2bf(v1.z); o.us[7] = f2bf(v1.w);
  *(uint4*)dst = o.v;
}

// ---------------------------------------------------------------------------
// C[M,1024] = A[M,1024] x Bw[1024,1024]^T (+bias). Bw is [N][K] (torch Linear).
// 128x128 tile, BK=64, 4 waves, 16x16x32 MFMA, XOR-swizzled LDS (rule #21).
// MODE 0: f32 out row-major (+bias)
// MODE 1: bf16 (acc+bias)*0.125*log2e -> qh[b][n][i][d]  (scores in log2 units)
template <int MODE>
__global__ __launch_bounds__(256, 2) void gemm_bt(
    const unsigned short* __restrict__ A, const unsigned short* __restrict__ Bw,
    const float* __restrict__ bias, void* __restrict__ outp) {
  __shared__ __align__(16) unsigned short lA[128 * 64];
  __shared__ __align__(16) unsigned short lB[128 * 64];
  const int tid = threadIdx.x;
  const int lane = tid & 63;
  const int w = tid >> 6;
  const int wr = w >> 1, wcn = w & 1;
  const int tm = blockIdx.x * 128;
  const int tn = blockIdx.y * 128;

  const int srow = lane >> 3;
  const int scol = ((lane & 7) ^ srow) * 8;
  const unsigned short* aptr = A + (size_t)(tm + 32 * w + srow) * 1024 + scol;
  const unsigned short* bptr = Bw + (size_t)(tn + 32 * w + srow) * 1024 + scol;
  unsigned short* lAw = &lA[(32 * w) * 64];
  unsigned short* lBw = &lB[(32 * w) * 64];

  const f32x4 zero = {0.f, 0.f, 0.f, 0.f};
  f32x4 acc[4][4];
#pragma unroll
  for (int i = 0; i < 4; ++i)
#pragma unroll
    for (int j = 0; j < 4; ++j) acc[i][j] = zero;

  for (int kb = 0; kb < 16; ++kb) {
    const int ko = kb * 64;
#pragma unroll
    for (int c = 0; c < 4; ++c) {
      gload_lds16(aptr + ko + c * 8 * 1024, lAw + c * 8 * 64);
      gload_lds16(bptr + ko + c * 8 * 1024, lBw + c * 8 * 64);
    }
    __syncthreads();
#pragma unroll
    for (int kk = 0; kk < 2; ++kk) {
      short8 af[4], bfr[4];
#pragma unroll
      for (int mi = 0; mi < 4; ++mi) {
        int r = 64 * wr + 16 * mi + (lane & 15);
        int slot = (kk * 4 + (lane >> 4)) ^ (r & 7);
        af[mi] = *(const short8*)&lA[r * 64 + slot * 8];
      }
#pragma unroll
      for (int ni = 0; ni < 4; ++ni) {
        int r = 64 * wcn + 16 * ni + (lane & 15);
        int slot = (kk * 4 + (lane >> 4)) ^ (r & 7);
        bfr[ni] = *(const short8*)&lB[r * 64 + slot * 8];
      }
#pragma unroll
      for (int mi = 0; mi < 4; ++mi)
#pragma unroll
        for (int ni = 0; ni < 4; ++ni)
          acc[mi][ni] = __builtin_amdgcn_mfma_f32_16x16x32_bf16(
              af[mi], bfr[ni], acc[mi][ni], 0, 0, 0);
    }
    __syncthreads();
  }

  const int g4 = (lane >> 4) * 4;
  const int c0 = lane & 15;
#pragma unroll
  for (int mi = 0; mi < 4; ++mi) {
#pragma unroll
    for (int ni = 0; ni < 4; ++ni) {
      const int colt = tn + 64 * wcn + 16 * ni + c0;
      const float bv = bias[colt];
#pragma unroll
      for (int j = 0; j < 4; ++j) {
        const int rowt = tm + 64 * wr + 16 * mi + g4 + j;
        const float v = acc[mi][ni][j] + bv;
        if constexpr (MODE == 0) {
          ((float*)outp)[(size_t)rowt * 1024 + colt] = v;
        } else {
          const int i = rowt >> 1, b = rowt & 1, n = colt >> 6, d = colt & 63;
          ((unsigned short*)outp)[(((size_t)(b * 16 + n) * 2048 + i) << 6) + d] =
              f2bf(v * 0.1803368801111f);  // 1/8 * log2(e): exp2-direct scores
        }
      }
    }
  }
}

// ---------------------------------------------------------------------------
// Merged K/V projection: one dispatch, grid (64, 16). Blocks y<8 compute K
// (-> kh[b][n][j][d]); y>=8 compute V (-> vt[b][n][d][pi(j)], j permuted so
// attn's PV fragment is one b128 read). Same tile structure as gemm_bt.
__global__ __launch_bounds__(256, 2) void gemm_kv(
    const unsigned short* __restrict__ A, const unsigned short* __restrict__ wk,
    const unsigned short* __restrict__ wv, const float* __restrict__ bk,
    const float* __restrict__ bv, unsigned short* __restrict__ ko,
    unsigned short* __restrict__ vo) {
  __shared__ __align__(16) unsigned short lA[128 * 64];
  __shared__ __align__(16) unsigned short lB[128 * 64];
  const int tid = threadIdx.x;
  const int lane = tid & 63;
  const int w = tid >> 6;
  const int wr = w >> 1, wcn = w & 1;
  const int tm = blockIdx.x * 128;
  const int yy = blockIdx.y;
  const bool isV = yy >= 8;
  const int tn = (yy & 7) * 128;
  const unsigned short* Bw = isV ? wv : wk;
  const float* bias = isV ? bv : bk;

  const int srow = lane >> 3;
  const int scol = ((lane & 7) ^ srow) * 8;
  const unsigned short* aptr = A + (size_t)(tm + 32 * w + srow) * 1024 + scol;
  const unsigned short* bptr = Bw + (size_t)(tn + 32 * w + srow) * 1024 + scol;
  unsigned short* lAw = &lA[(32 * w) * 64];
  unsigned short* lBw = &lB[(32 * w) * 64];

  const f32x4 zero = {0.f, 0.f, 0.f, 0.f};
  f32x4 acc[4][4];
#pragma unroll
  for (int i = 0; i < 4; ++i)
#pragma unroll
    for (int j = 0; j < 4; ++j) acc[i][j] = zero;

  for (int kb = 0; kb < 16; ++kb) {
    const int ko_ = kb * 64;
#pragma unroll
    for (int c = 0; c < 4; ++c) {
      gload_lds16(aptr + ko_ + c * 8 * 1024, lAw + c * 8 * 64);
      gload_lds16(bptr + ko_ + c * 8 * 1024, lBw + c * 8 * 64);
    }
    __syncthreads();
#pragma unroll
    for (int kk = 0; kk < 2; ++kk) {
      short8 af[4], bfr[4];
#pragma unroll
      for (int mi = 0; mi < 4; ++mi) {
        int r = 64 * wr + 16 * mi + (lane & 15);
        int slot = (kk * 4 + (lane >> 4)) ^ (r & 7);
        af[mi] = *(const short8*)&lA[r * 64 + slot * 8];
      }
#pragma unroll
      for (int ni = 0; ni < 4; ++ni) {
        int r = 64 * wcn + 16 * ni + (lane & 15);
        int slot = (kk * 4 + (lane >> 4)) ^ (r & 7);
        bfr[ni] = *(const short8*)&lB[r * 64 + slot * 8];
      }
#pragma unroll
      for (int mi = 0; mi < 4; ++mi)
#pragma unroll
        for (int ni = 0; ni < 4; ++ni)
          acc[mi][ni] = __builtin_amdgcn_mfma_f32_16x16x32_bf16(
              af[mi], bfr[ni], acc[mi][ni], 0, 0, 0);
    }
    __syncthreads();
  }

  const int g4 = (lane >> 4) * 4;
  const int c0 = lane & 15;
#pragma unroll
  for (int mi = 0; mi < 4; ++mi) {
#pragma unroll
    for (int ni = 0; ni < 4; ++ni) {
      const int colt = tn + 64 * wcn + 16 * ni + c0;
      const float bvv = bias[colt];
#pragma unroll
      for (int j = 0; j < 4; ++j) {
        const int rowt = tm + 64 * wr + 16 * mi + g4 + j;
        const float v = acc[mi][ni][j] + bvv;
        const int jj = rowt >> 1, b = rowt & 1, n = colt >> 6, d = colt & 63;
        if (!isV) {
          ko[(((size_t)(b * 16 + n) * 4096 + jj) << 6) + d] = f2bf(v);
        } else {
          const int j6 = jj & 63;
          const int pos = (j6 & 3) | (((j6 >> 4) & 1) << 2) | (((j6 >> 2) & 3) << 3) |
                          (((j6 >> 5) & 1) << 5);
          vo[((size_t)(b * 16 + n) * 64 + d) * 4096 + (jj & ~63) + pos] = f2bf(v);
        }
      }
    }
  }
}

// ---------------------------------------------------------------------------
// Flash attention. Block = (head, 128-row q-tile): 256 threads / 4 waves,
// 32 q-rows per wave (mi=0,1). Grid 512 = 2 blocks/CU.
// K: GLOBAL->REGISTER (L2-served; rotating krA/krB, prefetch dist = 1
// subtile, compiler-managed waits). V: LDS, double-buffered pairs,
// pre-permuted so PV B-frag is one ds_read_b128.
// S^T = mfma(K,Q): lane holds j=16nj+4g+reg of columns i=16mi+l4.
// Defer-max softmax; l as per-lane partials, epilogue reduce.
// XCD map: f&7 = xcd -> per XCD 4 heads x 16 q-tiles, ~4MB L2 working set.
__global__ __launch_bounds__(256, 2) void attn_kernel(
    const unsigned short* __restrict__ qh, const unsigned short* __restrict__ kh,
    const unsigned short* __restrict__ vt, unsigned short* __restrict__ vec) {
  __shared__ __align__(16) unsigned short vl[2][2][64 * 64];
  const int tid = threadIdx.x;
  const int lane = tid & 63;
  const int w = tid >> 6;  // 0..3
  const int g = lane >> 4;
  const int l4 = lane & 15;
  // f = [qt(4) | head_lo(2) | xcd(3)]: per XCD, 4 heads x 16 q-tiles
  const int f = blockIdx.x;
  const int head = (f & 7) * 4 + ((f >> 3) & 3);
  const int qt = f >> 5;  // 0..15
  const int b = head >> 4, n = head & 15;
  const unsigned short* qbase = qh + ((size_t)head * 2048 + qt * 128 + 32 * w) * 64;
  const unsigned short* kbase = kh + (size_t)head * 4096 * 64;
  const unsigned short* vbase = vt + (size_t)head * 64 * 4096;

  // Q fragments: 32 rows per wave (A-layout of Q == B-layout of Q^T)
  short8 qf[2][2];
#pragma unroll
  for (int mi = 0; mi < 2; ++mi)
#pragma unroll
    for (int kk = 0; kk < 2; ++kk)
      qf[mi][kk] = *(const short8*)&qbase[(16 * mi + l4) * 64 + kk * 32 + g * 8];

  const f32x4 zero = {0.f, 0.f, 0.f, 0.f};
  f32x4 oacc[2][4];
#pragma unroll
  for (int mi = 0; mi < 2; ++mi)
#pragma unroll
    for (int nd = 0; nd < 4; ++nd) oacc[mi][nd] = zero;
  float mrow[2] = {-3.0e38f, -3.0e38f};  // running max of col i=16mi+l4 (log2)
  float lsum[2] = {0.f, 0.f};            // per-lane partial denominators

  const int srow = lane >> 3;
  const int scol = ((lane & 7) ^ srow) * 8;
  const unsigned short* vp = vbase + (size_t)(16 * w + srow) * 4096 + scol;
  // per-lane K fragment base: row l4 (within 16-row group), elems g*8..
  const unsigned short* kfrag = kbase + (size_t)l4 * 64 + g * 8;

  // stage V of one pair (j-tiles 2jp, 2jp+1) into buffer bufi: 4 gloads/wave
  auto stage_pairV = [&](int jp, int bufi) {
#pragma unroll
    for (int sub = 0; sub < 2; ++sub) {
      gload_lds16(vp + jp * 128 + sub * 64, &vl[bufi][sub][(16 * w) * 64]);
      gload_lds16(vp + jp * 128 + sub * 64 + 8 * 4096,
                  &vl[bufi][sub][(16 * w + 8) * 64]);
    }
  };

  // K fragments of subtile jt -> registers (plain loads, compiler-scheduled)
  auto kload = [&](int jt, short8 (&kr)[2][4]) {
    const unsigned short* p = kfrag + (size_t)jt * 4096;
#pragma unroll
    for (int kk = 0; kk < 2; ++kk)
#pragma unroll
      for (int nj = 0; nj < 4; ++nj)
        kr[kk][nj] = *(const short8*)&p[nj * 1024 + kk * 32];
  };

  // one 64-j subtile: QK^T (K from regs) -> defer-max softmax -> P -> PV
  auto subtile = [&](const short8 (&kr)[2][4], const unsigned short* vbuf) {
    f32x4 s[2][4];
#pragma unroll
    for (int mi = 0; mi < 2; ++mi)
#pragma unroll
      for (int nj = 0; nj < 4; ++nj) s[mi][nj] = zero;
    __builtin_amdgcn_s_setprio(1);
#pragma unroll
    for (int kk = 0; kk < 2; ++kk)
#pragma unroll
      for (int mi = 0; mi < 2; ++mi)
#pragma unroll
        for (int nj = 0; nj < 4; ++nj)
          s[mi][nj] = __builtin_amdgcn_mfma_f32_16x16x32_bf16(
              kr[kk][nj], qf[mi][kk], s[mi][nj], 0, 0, 0);
    __builtin_amdgcn_s_setprio(0);

    // per-mi 16-max via v_max3, then joint pmax (one cross-lane pair)
    float pm[2];
#pragma unroll
    for (int mi = 0; mi < 2; ++mi) {
      float t0 = max3f(s[mi][0][0], s[mi][0][1], s[mi][0][2]);
      float t1 = max3f(s[mi][0][3], s[mi][1][0], s[mi][1][1]);
      float t2 = max3f(s[mi][1][2], s[mi][1][3], s[mi][2][0]);
      float t3 = max3f(s[mi][2][1], s[mi][2][2], s[mi][2][3]);
      float t4 = max3f(s[mi][3][0], s[mi][3][1], s[mi][3][2]);
      float p5 = max3f(t0, t1, t2);
      p5 = max3f(p5, t3, t4);
      pm[mi] = fmaxf(p5, s[mi][3][3]);
    }
    float pj = fmaxf(pm[0], pm[1]);
    pj = fmaxf(pj, __shfl_xor(pj, 16));
    pj = fmaxf(pj, __shfl_xor(pj, 32));
    if (!__all(pj <= fminf(mrow[0], mrow[1]) + 8.f)) {  // defer-max (T13)
#pragma unroll
      for (int mi = 0; mi < 2; ++mi) {
        const float mnew = fmaxf(mrow[mi], pj);  // joint max: >= per-col, safe
        const float sc = __builtin_amdgcn_exp2f(mrow[mi] - mnew);
        mrow[mi] = mnew;
        lsum[mi] *= sc;
#pragma unroll
        for (int reg = 0; reg < 4; ++reg) {
          const float scr = __shfl(sc, 4 * g + reg);
#pragma unroll
          for (int nd = 0; nd < 4; ++nd) oacc[mi][nd][reg] *= scr;
        }
      }
    }
    short8 pa[2][2];
#pragma unroll
    for (int mi = 0; mi < 2; ++mi) {
      const float m = mrow[mi];
      float tr[4];
#pragma unroll
      for (int nj = 0; nj < 4; ++nj) {
        const float p0 = __builtin_amdgcn_exp2f(s[mi][nj][0] - m);
        const float p1 = __builtin_amdgcn_exp2f(s[mi][nj][1] - m);
        const float p2 = __builtin_amdgcn_exp2f(s[mi][nj][2] - m);
        const float p3 = __builtin_amdgcn_exp2f(s[mi][nj][3] - m);
        s[mi][nj][0] = p0; s[mi][nj][1] = p1; s[mi][nj][2] = p2; s[mi][nj][3] = p3;
        tr[nj] = (p0 + p1) + (p2 + p3);  // tree, not serial chain
      }
      lsum[mi] += (tr[0] + tr[1]) + (tr[2] + tr[3]);
      // pack P lane-locally: slot e of chunk kk2 -> j = 4g+(e&3)+16(e>>2)+32kk2
#pragma unroll
      for (int kk2 = 0; kk2 < 2; ++kk2) {
        union { unsigned int u[4]; short8 v; } t;
#pragma unroll
        for (int wd = 0; wd < 4; ++wd) {
          const int nj = (wd >> 1) + 2 * kk2;
          const int r0 = (wd & 1) * 2;
          t.u[wd] = cvtpk(s[mi][nj][r0], s[mi][nj][r0 + 1]);
        }
        pa[mi][kk2] = t.v;
      }
    }

    // O += P V; V rows pre-permuted so the 8 k-slots of (g,kk2) are one
    // contiguous 16B block; bv4 shared by both mi
    __builtin_amdgcn_s_setprio(1);
#pragma unroll
    for (int kk2 = 0; kk2 < 2; ++kk2) {
      short8 bv4[4];
#pragma unroll
      for (int nd = 0; nd < 4; ++nd) {
        const int r = 16 * nd + l4;
        const int blk = (g + 4 * kk2) ^ (r & 7);
        bv4[nd] = *(const short8*)&vbuf[r * 64 + blk * 8];
      }
#pragma unroll
      for (int mi = 0; mi < 2; ++mi)
#pragma unroll
        for (int nd = 0; nd < 4; ++nd)
          oacc[mi][nd] = __builtin_amdgcn_mfma_f32_16x16x32_bf16(
              pa[mi][kk2], bv4[nd], oacc[mi][nd], 0, 0, 0);
    }
    __builtin_amdgcn_s_setprio(0);
  };

  // rotating K register buffers: krA = even subtiles, krB = odd
  short8 krA[2][4], krB[2][4];

  // prologue: stage V pair 0; K subtile 0 -> regs; drain V (and qf/K loads)
  stage_pairV(0, 0);
  kload(0, krA);
  asm volatile("s_waitcnt vmcnt(0)" ::: "memory");
  BARRIER_RAW();

  // 32 pairs, unrolled x2 so all buffer names are compile-time constants
  for (int t2 = 0; t2 < 16; ++t2) {
    // pair 2*t2 (V in vl[0]): subtiles 4t2, 4t2+1
    stage_pairV(2 * t2 + 1, 1);
    kload(4 * t2 + 1, krB);
    subtile(krA, vl[0][0]);
    kload(4 * t2 + 2, krA);
    subtile(krB, vl[0][1]);
    asm volatile("s_waitcnt vmcnt(0)" ::: "memory");
    BARRIER_RAW();
    // pair 2*t2+1 (V in vl[1]): subtiles 4t2+2, 4t2+3
    if (t2 < 15) stage_pairV(2 * t2 + 2, 0);
    kload(4 * t2 + 3, krB);
    subtile(krA, vl[1][0]);
    if (t2 < 15) kload(4 * t2 + 4, krA);
    subtile(krB, vl[1][1]);
    if (t2 < 15) {
      asm volatile("s_waitcnt vmcnt(0)" ::: "memory");
      BARRIER_RAW();
    }
  }

  // epilogue: reduce per-lane l partials, rows 4g+reg read their l by shfl
#pragma unroll
  for (int mi = 0; mi < 2; ++mi) {
    float l = lsum[mi];
    l += __shfl_xor(l, 16);
    l += __shfl_xor(l, 32);
#pragma unroll
    for (int reg = 0; reg < 4; ++reg) {
      const float lr = __shfl(l, 4 * g + reg);
      const float inv = 1.f / lr;
      const int i = qt * 128 + 32 * w + 16 * mi + 4 * g + reg;
#pragma unroll
      for (int nd = 0; nd < 4; ++nd) {
        const int d = 16 * nd + l4;
        vec[(size_t)(i * 2 + b) * 1024 + n * 64 + d] = f2bf(oacc[mi][nd][reg] * inv);
      }
    }
  }
}

// ---------------------------------------------------------------------------
extern "C" void kernel_launch(void* const* d_in, const int* in_sizes, int n_in,
                              void* d_out, int out_size, void* d_ws, size_t ws_size,
                              hipStream_t stream) {
  (void)in_sizes; (void)n_in; (void)out_size; (void)ws_size;
  const float* q    = (const float*)d_in[0];
  const float* kv   = (const float*)d_in[1];
  const float* mem_ = (const float*)d_in[2];
  const float* wq   = (const float*)d_in[3];
  const float* bq   = (const float*)d_in[4];
  const float* wk   = (const float*)d_in[5];
  const float* bk   = (const float*)d_in[6];
  const float* wv   = (const float*)d_in[7];
  const float* bv   = (const float*)d_in[8];
  const float* wc   = (const float*)d_in[9];
  const float* bc   = (const float*)d_in[10];

  char* ws = (char*)d_ws;
  unsigned short* w_bf = (unsigned short*)(ws);                       // 8 MB: wq,wk,wv,wc
  unsigned short* a_bf = (unsigned short*)(ws + (8ull << 20));        // 8 MB: q bf16 [4096][1024]
  unsigned short* c_bf = (unsigned short*)(ws + (16ull << 20));       // 16 MB: concat(mem,kv)
  unsigned short* qhb  = (unsigned short*)(ws + (32ull << 20));       // 8 MB: [b][n][2048][64]
  unsigned short* khb  = (unsigned short*)(ws + (40ull << 20));       // 16 MB: [b][n][4096][64]
  unsigned short* vtb  = (unsigned short*)(ws + (56ull << 20));       // 16 MB: [b][n][64][pi(j)]
  unsigned short* vecb = a_bf;  // reuse (a_bf dead after Q projection)

  convert_all<<<8192, 256, 0, stream>>>(q, mem_, kv, wq, wk, wv, wc, a_bf, c_bf, w_bf);
  gemm_bt<1><<<dim3(32, 8), 256, 0, stream>>>(a_bf, w_bf, bq, qhb);
  gemm_kv<<<dim3(64, 16), 256, 0, stream>>>(c_bf, w_bf + (1u << 20), w_bf + (2u << 20),
                                            bk, bv, khb, vtb);
  attn_kernel<<<512, 256, 0, stream>>>(qhb, khb, vtb, vecb);
  gemm_bt<0><<<dim3(32, 8), 256, 0, stream>>>(vecb, w_bf + (3u << 20), bc, d_out);
}

// Round 12
// 177.491 us; speedup vs baseline: 1.3027x; 1.3027x over previous
//
#include <hip/hip_runtime.h>

// XL-attention: out = (softmax(Qh Kh^T / 8) Vh) @ Wc^T + bc
// L=2048, B=2, M=2048 -> J=4096, D=1024, H=16, Dh=64.
// All matmuls in bf16 MFMA (16x16x32), f32 accumulate.
// Attention (round-10 proven): swapped QK^T, in-register defer-max softmax,
// in-register P, 4-wave blocks, 32 q-rows/wave, pair-pipelined subtiles,
// V pre-permuted so PV B-frag is one ds_read_b128.
// All three projections (Q,K,V) merged into ONE dispatch (1280 active
// blocks = 5/CU) for occupancy + L2 co-residency.

using short8 = __attribute__((ext_vector_type(8))) short;
using f32x4  = __attribute__((ext_vector_type(4))) float;

#define DEV __device__ __forceinline__

DEV unsigned short f2bf(float f) {
  union { float f; unsigned int u; } x; x.f = f;
  unsigned int r = x.u + 0x7FFFu + ((x.u >> 16) & 1u);
  return (unsigned short)(r >> 16);
}

DEV unsigned int cvtpk(float lo, float hi) {
  unsigned int r;
  asm("v_cvt_pk_bf16_f32 %0, %1, %2" : "=v"(r) : "v"(lo), "v"(hi));
  return r;
}

DEV float max3f(float a, float b, float c) {
  float d;
  asm("v_max3_f32 %0, %1, %2, %3" : "=v"(d) : "v"(a), "v"(b), "v"(c));
  return d;
}

DEV void gload_lds16(const unsigned short* g, unsigned short* l) {
  __builtin_amdgcn_global_load_lds(
      (const __attribute__((address_space(1))) unsigned int*)g,
      (__attribute__((address_space(3))) unsigned int*)l, 16, 0, 0);
}

#define BARRIER_RAW()                      \
  do {                                     \
    __builtin_amdgcn_sched_barrier(0);     \
    __builtin_amdgcn_s_barrier();          \
    __builtin_amdgcn_sched_barrier(0);     \
  } while (0)

// ---------------------------------------------------------------------------
// f32 -> bf16 conversion of all inputs (q, concat(mem,kv), 4 weights)
__global__ __launch_bounds__(256) void convert_all(
    const float* __restrict__ q, const float* __restrict__ mem_,
    const float* __restrict__ kv, const float* __restrict__ wq,
    const float* __restrict__ wk, const float* __restrict__ wv,
    const float* __restrict__ wc, unsigned short* __restrict__ a_bf,
    unsigned short* __restrict__ c_bf, unsigned short* __restrict__ w_bf) {
  size_t u = (size_t)blockIdx.x * 256 + threadIdx.x;
  const float* src;
  unsigned short* dst;
  if (u < 524288u)        { src = q    + u * 8;                dst = a_bf + u * 8; }
  else if (u < 1048576u)  { src = mem_ + (u - 524288u) * 8;    dst = c_bf + (u - 524288u) * 8; }
  else if (u < 1572864u)  { src = kv   + (u - 1048576u) * 8;   dst = c_bf + 4194304u + (u - 1048576u) * 8; }
  else if (u < 1703936u)  { src = wq   + (u - 1572864u) * 8;   dst = w_bf + (u - 1572864u) * 8; }
  else if (u < 1835008u)  { src = wk   + (u - 1703936u) * 8;   dst = w_bf + 1048576u + (u - 1703936u) * 8; }
  else if (u < 1966080u)  { src = wv   + (u - 1835008u) * 8;   dst = w_bf + 2097152u + (u - 1835008u) * 8; }
  else                    { src = wc   + (u - 1966080u) * 8;   dst = w_bf + 3145728u + (u - 1966080u) * 8; }
  float4 v0 = ((const float4*)src)[0];
  float4 v1 = ((const float4*)src)[1];
  union { unsigned short us[8]; uint4 v; } o;
  o.us[0] = f2bf(v0.x); o.us[1] = f2bf(v0.y); o.us[2] = f2bf(v0.z); o.us[3] = f2bf(v0.w);
  o.us[4] = f2bf(v1.x); o.us[5] = f2bf(v1.y); o.us[6] = f2bf(v1.z); o.us[7] = f2bf(v1.w);
  *(uint4*)dst = o.v;
}

// ---------------------------------------------------------------------------
// Output projection: C[4096,1024] f32 = A x Wc^T + bc. 128x128 tile, BK=64,
// 4 waves, XOR-swizzled LDS (rule #21).
__global__ __launch_bounds__(256, 2) void gemm_out(
    const unsigned short* __restrict__ A, const unsigned short* __restrict__ Bw,
    const float* __restrict__ bias, float* __restrict__ outp) {
  __shared__ __align__(16) unsigned short lA[128 * 64];
  __shared__ __align__(16) unsigned short lB[128 * 64];
  const int tid = threadIdx.x;
  const int lane = tid & 63;
  const int w = tid >> 6;
  const int wr = w >> 1, wcn = w & 1;
  const int tm = blockIdx.x * 128;
  const int tn = blockIdx.y * 128;

  const int srow = lane >> 3;
  const int scol = ((lane & 7) ^ srow) * 8;
  const unsigned short* aptr = A + (size_t)(tm + 32 * w + srow) * 1024 + scol;
  const unsigned short* bptr = Bw + (size_t)(tn + 32 * w + srow) * 1024 + scol;
  unsigned short* lAw = &lA[(32 * w) * 64];
  unsigned short* lBw = &lB[(32 * w) * 64];

  const f32x4 zero = {0.f, 0.f, 0.f, 0.f};
  f32x4 acc[4][4];
#pragma unroll
  for (int i = 0; i < 4; ++i)
#pragma unroll
    for (int j = 0; j < 4; ++j) acc[i][j] = zero;

  for (int kb = 0; kb < 16; ++kb) {
    const int ko = kb * 64;
#pragma unroll
    for (int c = 0; c < 4; ++c) {
      gload_lds16(aptr + ko + c * 8 * 1024, lAw + c * 8 * 64);
      gload_lds16(bptr + ko + c * 8 * 1024, lBw + c * 8 * 64);
    }
    __syncthreads();
#pragma unroll
    for (int kk = 0; kk < 2; ++kk) {
      short8 af[4], bfr[4];
#pragma unroll
      for (int mi = 0; mi < 4; ++mi) {
        int r = 64 * wr + 16 * mi + (lane & 15);
        int slot = (kk * 4 + (lane >> 4)) ^ (r & 7);
        af[mi] = *(const short8*)&lA[r * 64 + slot * 8];
      }
#pragma unroll
      for (int ni = 0; ni < 4; ++ni) {
        int r = 64 * wcn + 16 * ni + (lane & 15);
        int slot = (kk * 4 + (lane >> 4)) ^ (r & 7);
        bfr[ni] = *(const short8*)&lB[r * 64 + slot * 8];
      }
#pragma unroll
      for (int mi = 0; mi < 4; ++mi)
#pragma unroll
        for (int ni = 0; ni < 4; ++ni)
          acc[mi][ni] = __builtin_amdgcn_mfma_f32_16x16x32_bf16(
              af[mi], bfr[ni], acc[mi][ni], 0, 0, 0);
    }
    __syncthreads();
  }

  const int g4 = (lane >> 4) * 4;
  const int c0 = lane & 15;
#pragma unroll
  for (int mi = 0; mi < 4; ++mi) {
#pragma unroll
    for (int ni = 0; ni < 4; ++ni) {
      const int colt = tn + 64 * wcn + 16 * ni + c0;
      const float bv = bias[colt];
#pragma unroll
      for (int j = 0; j < 4; ++j) {
        const int rowt = tm + 64 * wr + 16 * mi + g4 + j;
        outp[(size_t)rowt * 1024 + colt] = acc[mi][ni][j] + bv;
      }
    }
  }
}

// ---------------------------------------------------------------------------
// Merged Q/K/V projection: one dispatch, grid (64, 24).
// y in [0,8): K  -> kh[b][n][j][d]                 (A = c_bf, M=8192)
// y in [8,16): V -> vt[b][n][d][pi(j)]             (A = c_bf, M=8192)
// y in [16,24): Q -> qh[b][n][i][d] * 0.125*log2e  (A = a_bf, M=4096; x<32)
// 1280 active blocks = 5/CU. Same proven tile structure.
__global__ __launch_bounds__(256, 2) void gemm_proj(
    const unsigned short* __restrict__ a_bf, const unsigned short* __restrict__ c_bf,
    const unsigned short* __restrict__ w_bf, const float* __restrict__ bq,
    const float* __restrict__ bk, const float* __restrict__ bv,
    unsigned short* __restrict__ qh, unsigned short* __restrict__ kh,
    unsigned short* __restrict__ vt) {
  const int yy = blockIdx.y;
  const int mode = yy >> 3;  // 0=K, 1=V, 2=Q
  if (mode == 2 && blockIdx.x >= 32) return;
  __shared__ __align__(16) unsigned short lA[128 * 64];
  __shared__ __align__(16) unsigned short lB[128 * 64];
  const int tid = threadIdx.x;
  const int lane = tid & 63;
  const int w = tid >> 6;
  const int wr = w >> 1, wcn = w & 1;
  const int tm = blockIdx.x * 128;
  const int tn = (yy & 7) * 128;
  const unsigned short* A  = (mode == 2) ? a_bf : c_bf;
  const unsigned short* Bw = (mode == 0) ? w_bf + (1u << 20)
                            : (mode == 1) ? w_bf + (2u << 20) : w_bf;
  const float* bias = (mode == 0) ? bk : (mode == 1) ? bv : bq;

  const int srow = lane >> 3;
  const int scol = ((lane & 7) ^ srow) * 8;
  const unsigned short* aptr = A + (size_t)(tm + 32 * w + srow) * 1024 + scol;
  const unsigned short* bptr = Bw + (size_t)(tn + 32 * w + srow) * 1024 + scol;
  unsigned short* lAw = &lA[(32 * w) * 64];
  unsigned short* lBw = &lB[(32 * w) * 64];

  const f32x4 zero = {0.f, 0.f, 0.f, 0.f};
  f32x4 acc[4][4];
#pragma unroll
  for (int i = 0; i < 4; ++i)
#pragma unroll
    for (int j = 0; j < 4; ++j) acc[i][j] = zero;

  for (int kb = 0; kb < 16; ++kb) {
    const int ko = kb * 64;
#pragma unroll
    for (int c = 0; c < 4; ++c) {
      gload_lds16(aptr + ko + c * 8 * 1024, lAw + c * 8 * 64);
      gload_lds16(bptr + ko + c * 8 * 1024, lBw + c * 8 * 64);
    }
    __syncthreads();
#pragma unroll
    for (int kk = 0; kk < 2; ++kk) {
      short8 af[4], bfr[4];
#pragma unroll
      for (int mi = 0; mi < 4; ++mi) {
        int r = 64 * wr + 16 * mi + (lane & 15);
        int slot = (kk * 4 + (lane >> 4)) ^ (r & 7);
        af[mi] = *(const short8*)&lA[r * 64 + slot * 8];
      }
#pragma unroll
      for (int ni = 0; ni < 4; ++ni) {
        int r = 64 * wcn + 16 * ni + (lane & 15);
        int slot = (kk * 4 + (lane >> 4)) ^ (r & 7);
        bfr[ni] = *(const short8*)&lB[r * 64 + slot * 8];
      }
#pragma unroll
      for (int mi = 0; mi < 4; ++mi)
#pragma unroll
        for (int ni = 0; ni < 4; ++ni)
          acc[mi][ni] = __builtin_amdgcn_mfma_f32_16x16x32_bf16(
              af[mi], bfr[ni], acc[mi][ni], 0, 0, 0);
    }
    __syncthreads();
  }

  const int g4 = (lane >> 4) * 4;
  const int c0 = lane & 15;
#pragma unroll
  for (int mi = 0; mi < 4; ++mi) {
#pragma unroll
    for (int ni = 0; ni < 4; ++ni) {
      const int colt = tn + 64 * wcn + 16 * ni + c0;
      const float bvv = bias[colt];
#pragma unroll
      for (int j = 0; j < 4; ++j) {
        const int rowt = tm + 64 * wr + 16 * mi + g4 + j;
        const float v = acc[mi][ni][j] + bvv;
        const int jj = rowt >> 1, b = rowt & 1, n = colt >> 6, d = colt & 63;
        if (mode == 0) {
          kh[(((size_t)(b * 16 + n) * 4096 + jj) << 6) + d] = f2bf(v);
        } else if (mode == 1) {
          const int j6 = jj & 63;
          const int pos = (j6 & 3) | (((j6 >> 4) & 1) << 2) | (((j6 >> 2) & 3) << 3) |
                          (((j6 >> 5) & 1) << 5);
          vt[((size_t)(b * 16 + n) * 64 + d) * 4096 + (jj & ~63) + pos] = f2bf(v);
        } else {
          qh[(((size_t)(b * 16 + n) * 2048 + jj) << 6) + d] =
              f2bf(v * 0.1803368801111f);  // 1/8 * log2(e): exp2-direct scores
        }
      }
    }
  }
}

// ---------------------------------------------------------------------------
// Flash attention (round-10 proven). Block = (head, 128-row q-tile):
// 256 threads / 4 waves, 32 q-rows per wave (mi=0,1). Grid 512 = 2 blocks/CU.
// Pair-pipelined: qkt(0); qkt(1); sm(0); pv(0); sm(1); pv(1).
// Defer-max softmax; l as per-lane partials (tree), epilogue reduce.
// V pre-permuted so PV B-frag is one ds_read_b128. XCD map: f&7 = xcd.
__global__ __launch_bounds__(256, 2) void attn_kernel(
    const unsigned short* __restrict__ qh, const unsigned short* __restrict__ kh,
    const unsigned short* __restrict__ vt, unsigned short* __restrict__ vec) {
  __shared__ __align__(16) unsigned short kl[2][2][64 * 64];
  __shared__ __align__(16) unsigned short vl[2][2][64 * 64];
  const int tid = threadIdx.x;
  const int lane = tid & 63;
  const int w = tid >> 6;  // 0..3
  const int g = lane >> 4;
  const int l4 = lane & 15;
  const int f = blockIdx.x;
  const int head = (f & 7) * 4 + ((f >> 3) & 3);
  const int qt = f >> 5;  // 0..15
  const int b = head >> 4, n = head & 15;
  const unsigned short* qbase = qh + ((size_t)head * 2048 + qt * 128 + 32 * w) * 64;
  const unsigned short* kbase = kh + (size_t)head * 4096 * 64;
  const unsigned short* vbase = vt + (size_t)head * 64 * 4096;

  short8 qf[2][2];
#pragma unroll
  for (int mi = 0; mi < 2; ++mi)
#pragma unroll
    for (int kk = 0; kk < 2; ++kk)
      qf[mi][kk] = *(const short8*)&qbase[(16 * mi + l4) * 64 + kk * 32 + g * 8];

  const f32x4 zero = {0.f, 0.f, 0.f, 0.f};
  f32x4 oacc[2][4];
#pragma unroll
  for (int mi = 0; mi < 2; ++mi)
#pragma unroll
    for (int nd = 0; nd < 4; ++nd) oacc[mi][nd] = zero;
  float mrow[2] = {-3.0e38f, -3.0e38f};
  float lsum[2] = {0.f, 0.f};

  const int srow = lane >> 3;
  const int scol = ((lane & 7) ^ srow) * 8;
  const unsigned short* kp = kbase + (size_t)(16 * w + srow) * 64 + scol;
  const unsigned short* vp = vbase + (size_t)(16 * w + srow) * 4096 + scol;

  auto stage_pair = [&](int jp, int bufi) {
#pragma unroll
    for (int sub = 0; sub < 2; ++sub) {
      gload_lds16(kp + (size_t)jp * 8192 + sub * 4096,
                  &kl[bufi][sub][(16 * w) * 64]);
      gload_lds16(kp + (size_t)jp * 8192 + sub * 4096 + 8 * 64,
                  &kl[bufi][sub][(16 * w + 8) * 64]);
      gload_lds16(vp + jp * 128 + sub * 64, &vl[bufi][sub][(16 * w) * 64]);
      gload_lds16(vp + jp * 128 + sub * 64 + 8 * 4096,
                  &vl[bufi][sub][(16 * w + 8) * 64]);
    }
  };

  auto qkt = [&](const unsigned short* kbuf, f32x4 (&s)[2][4]) {
#pragma unroll
    for (int mi = 0; mi < 2; ++mi)
#pragma unroll
      for (int nj = 0; nj < 4; ++nj) s[mi][nj] = zero;
    __builtin_amdgcn_s_setprio(1);
#pragma unroll
    for (int kk = 0; kk < 2; ++kk) {
      short8 bk[4];
#pragma unroll
      for (int nj = 0; nj < 4; ++nj) {
        int r = 16 * nj + l4;
        int slot = (kk * 4 + g) ^ (r & 7);
        bk[nj] = *(const short8*)&kbuf[r * 64 + slot * 8];
      }
#pragma unroll
      for (int mi = 0; mi < 2; ++mi)
#pragma unroll
        for (int nj = 0; nj < 4; ++nj)
          s[mi][nj] = __builtin_amdgcn_mfma_f32_16x16x32_bf16(bk[nj], qf[mi][kk], s[mi][nj], 0, 0, 0);
    }
    __builtin_amdgcn_s_setprio(0);
  };

  auto sm = [&](f32x4 (&s)[2][4], short8 (&pa)[2][2]) {
    float pm[2];
#pragma unroll
    for (int mi = 0; mi < 2; ++mi) {
      float t0 = max3f(s[mi][0][0], s[mi][0][1], s[mi][0][2]);
      float t1 = max3f(s[mi][0][3], s[mi][1][0], s[mi][1][1]);
      float t2 = max3f(s[mi][1][2], s[mi][1][3], s[mi][2][0]);
      float t3 = max3f(s[mi][2][1], s[mi][2][2], s[mi][2][3]);
      float t4 = max3f(s[mi][3][0], s[mi][3][1], s[mi][3][2]);
      float p5 = max3f(t0, t1, t2);
      p5 = max3f(p5, t3, t4);
      pm[mi] = fmaxf(p5, s[mi][3][3]);
    }
    float pj = fmaxf(pm[0], pm[1]);
    pj = fmaxf(pj, __shfl_xor(pj, 16));
    pj = fmaxf(pj, __shfl_xor(pj, 32));
    if (!__all(pj <= fminf(mrow[0], mrow[1]) + 8.f)) {
#pragma unroll
      for (int mi = 0; mi < 2; ++mi) {
        const float mnew = fmaxf(mrow[mi], pj);
        const float sc = __builtin_amdgcn_exp2f(mrow[mi] - mnew);
        mrow[mi] = mnew;
        lsum[mi] *= sc;
#pragma unroll
        for (int reg = 0; reg < 4; ++reg) {
          const float scr = __shfl(sc, 4 * g + reg);
#pragma unroll
          for (int nd = 0; nd < 4; ++nd) oacc[mi][nd][reg] *= scr;
        }
      }
    }
#pragma unroll
    for (int mi = 0; mi < 2; ++mi) {
      const float m = mrow[mi];
      float tr[4];
#pragma unroll
      for (int nj = 0; nj < 4; ++nj) {
        const float p0 = __builtin_amdgcn_exp2f(s[mi][nj][0] - m);
        const float p1 = __builtin_amdgcn_exp2f(s[mi][nj][1] - m);
        const float p2 = __builtin_amdgcn_exp2f(s[mi][nj][2] - m);
        const float p3 = __builtin_amdgcn_exp2f(s[mi][nj][3] - m);
        s[mi][nj][0] = p0; s[mi][nj][1] = p1; s[mi][nj][2] = p2; s[mi][nj][3] = p3;
        tr[nj] = (p0 + p1) + (p2 + p3);
      }
      lsum[mi] += (tr[0] + tr[1]) + (tr[2] + tr[3]);
#pragma unroll
      for (int kk2 = 0; kk2 < 2; ++kk2) {
        union { unsigned int u[4]; short8 v; } t;
#pragma unroll
        for (int wd = 0; wd < 4; ++wd) {
          const int nj = (wd >> 1) + 2 * kk2;
          const int r0 = (wd & 1) * 2;
          t.u[wd] = cvtpk(s[mi][nj][r0], s[mi][nj][r0 + 1]);
        }
        pa[mi][kk2] = t.v;
      }
    }
  };

  auto pv = [&](const short8 (&pa)[2][2], const unsigned short* vbuf) {
    __builtin_amdgcn_s_setprio(1);
#pragma unroll
    for (int kk2 = 0; kk2 < 2; ++kk2) {
      short8 bv4[4];
#pragma unroll
      for (int nd = 0; nd < 4; ++nd) {
        const int r = 16 * nd + l4;
        const int blk = (g + 4 * kk2) ^ (r & 7);
        bv4[nd] = *(const short8*)&vbuf[r * 64 + blk * 8];
      }
#pragma unroll
      for (int mi = 0; mi < 2; ++mi)
#pragma unroll
        for (int nd = 0; nd < 4; ++nd)
          oacc[mi][nd] = __builtin_amdgcn_mfma_f32_16x16x32_bf16(pa[mi][kk2], bv4[nd], oacc[mi][nd], 0, 0, 0);
    }
    __builtin_amdgcn_s_setprio(0);
  };

  f32x4 sA[2][4], sB[2][4];
  short8 paA[2][2], paB[2][2];
  auto pair = [&](int bufi) {
    qkt(kl[bufi][0], sA);
    qkt(kl[bufi][1], sB);
    sm(sA, paA);
    pv(paA, vl[bufi][0]);
    sm(sB, paB);
    pv(paB, vl[bufi][1]);
  };

  stage_pair(0, 0);
  asm volatile("s_waitcnt vmcnt(0)" ::: "memory");
  BARRIER_RAW();

  for (int t2 = 0; t2 < 16; ++t2) {
    stage_pair(2 * t2 + 1, 1);
    pair(0);
    asm volatile("s_waitcnt vmcnt(0)" ::: "memory");
    BARRIER_RAW();
    if (t2 < 15) stage_pair(2 * t2 + 2, 0);
    pair(1);
    if (t2 < 15) {
      asm volatile("s_waitcnt vmcnt(0)" ::: "memory");
      BARRIER_RAW();
    }
  }

#pragma unroll
  for (int mi = 0; mi < 2; ++mi) {
    float l = lsum[mi];
    l += __shfl_xor(l, 16);
    l += __shfl_xor(l, 32);
#pragma unroll
    for (int reg = 0; reg < 4; ++reg) {
      const float lr = __shfl(l, 4 * g + reg);
      const float inv = 1.f / lr;
      const int i = qt * 128 + 32 * w + 16 * mi + 4 * g + reg;
#pragma unroll
      for (int nd = 0; nd < 4; ++nd) {
        const int d = 16 * nd + l4;
        vec[(size_t)(i * 2 + b) * 1024 + n * 64 + d] = f2bf(oacc[mi][nd][reg] * inv);
      }
    }
  }
}

// ---------------------------------------------------------------------------
extern "C" void kernel_launch(void* const* d_in, const int* in_sizes, int n_in,
                              void* d_out, int out_size, void* d_ws, size_t ws_size,
                              hipStream_t stream) {
  (void)in_sizes; (void)n_in; (void)out_size; (void)ws_size;
  const float* q    = (const float*)d_in[0];
  const float* kv   = (const float*)d_in[1];
  const float* mem_ = (const float*)d_in[2];
  const float* wq   = (const float*)d_in[3];
  const float* bq   = (const float*)d_in[4];
  const float* wk   = (const float*)d_in[5];
  const float* bk   = (const float*)d_in[6];
  const float* wv   = (const float*)d_in[7];
  const float* bv   = (const float*)d_in[8];
  const float* wc   = (const float*)d_in[9];
  const float* bc   = (const float*)d_in[10];

  char* ws = (char*)d_ws;
  unsigned short* w_bf = (unsigned short*)(ws);                       // 8 MB: wq,wk,wv,wc
  unsigned short* a_bf = (unsigned short*)(ws + (8ull << 20));        // 8 MB: q bf16 [4096][1024]
  unsigned short* c_bf = (unsigned short*)(ws + (16ull << 20));       // 16 MB: concat(mem,kv)
  unsigned short* qhb  = (unsigned short*)(ws + (32ull << 20));       // 8 MB: [b][n][2048][64]
  unsigned short* khb  = (unsigned short*)(ws + (40ull << 20));       // 16 MB: [b][n][4096][64]
  unsigned short* vtb  = (unsigned short*)(ws + (56ull << 20));       // 16 MB: [b][n][64][pi(j)]
  unsigned short* vecb = a_bf;  // reuse (a_bf dead after Q projection)

  convert_all<<<8192, 256, 0, stream>>>(q, mem_, kv, wq, wk, wv, wc, a_bf, c_bf, w_bf);
  gemm_proj<<<dim3(64, 24), 256, 0, stream>>>(a_bf, c_bf, w_bf, bq, bk, bv,
                                              qhb, khb, vtb);
  attn_kernel<<<512, 256, 0, stream>>>(qhb, khb, vtb, vecb);
  gemm_out<<<dim3(32, 8), 256, 0, stream>>>(vecb, w_bf + (3u << 20), bc, (float*)d_out);
}

// Round 13
// 174.516 us; speedup vs baseline: 1.3249x; 1.0170x over previous
//
#include <hip/hip_runtime.h>

// XL-attention: out = (softmax(Qh Kh^T / 8) Vh) @ Wc^T + bc
// L=2048, B=2, M=2048 -> J=4096, D=1024, H=16, Dh=64.
// All matmuls in bf16 MFMA (16x16x32), f32 accumulate.
// Attention (round-10 proven): swapped QK^T, in-register defer-max softmax,
// in-register P, 4-wave blocks, 32 q-rows/wave, pair-pipelined subtiles,
// V pre-permuted so PV B-frag is one ds_read_b128.
// Q/K/V projections merged into ONE dispatch (5 blocks/CU).
// Output projection retiled 64x128 -> 512 blocks = 2/CU (was 1/CU).

using short8 = __attribute__((ext_vector_type(8))) short;
using f32x4  = __attribute__((ext_vector_type(4))) float;

#define DEV __device__ __forceinline__

DEV unsigned short f2bf(float f) {
  union { float f; unsigned int u; } x; x.f = f;
  unsigned int r = x.u + 0x7FFFu + ((x.u >> 16) & 1u);
  return (unsigned short)(r >> 16);
}

DEV unsigned int cvtpk(float lo, float hi) {
  unsigned int r;
  asm("v_cvt_pk_bf16_f32 %0, %1, %2" : "=v"(r) : "v"(lo), "v"(hi));
  return r;
}

DEV float max3f(float a, float b, float c) {
  float d;
  asm("v_max3_f32 %0, %1, %2, %3" : "=v"(d) : "v"(a), "v"(b), "v"(c));
  return d;
}

DEV void gload_lds16(const unsigned short* g, unsigned short* l) {
  __builtin_amdgcn_global_load_lds(
      (const __attribute__((address_space(1))) unsigned int*)g,
      (__attribute__((address_space(3))) unsigned int*)l, 16, 0, 0);
}

#define BARRIER_RAW()                      \
  do {                                     \
    __builtin_amdgcn_sched_barrier(0);     \
    __builtin_amdgcn_s_barrier();          \
    __builtin_amdgcn_sched_barrier(0);     \
  } while (0)

// ---------------------------------------------------------------------------
// f32 -> bf16 conversion of all inputs (q, concat(mem,kv), 4 weights)
__global__ __launch_bounds__(256) void convert_all(
    const float* __restrict__ q, const float* __restrict__ mem_,
    const float* __restrict__ kv, const float* __restrict__ wq,
    const float* __restrict__ wk, const float* __restrict__ wv,
    const float* __restrict__ wc, unsigned short* __restrict__ a_bf,
    unsigned short* __restrict__ c_bf, unsigned short* __restrict__ w_bf) {
  size_t u = (size_t)blockIdx.x * 256 + threadIdx.x;
  const float* src;
  unsigned short* dst;
  if (u < 524288u)        { src = q    + u * 8;                dst = a_bf + u * 8; }
  else if (u < 1048576u)  { src = mem_ + (u - 524288u) * 8;    dst = c_bf + (u - 524288u) * 8; }
  else if (u < 1572864u)  { src = kv   + (u - 1048576u) * 8;   dst = c_bf + 4194304u + (u - 1048576u) * 8; }
  else if (u < 1703936u)  { src = wq   + (u - 1572864u) * 8;   dst = w_bf + (u - 1572864u) * 8; }
  else if (u < 1835008u)  { src = wk   + (u - 1703936u) * 8;   dst = w_bf + 1048576u + (u - 1703936u) * 8; }
  else if (u < 1966080u)  { src = wv   + (u - 1835008u) * 8;   dst = w_bf + 2097152u + (u - 1835008u) * 8; }
  else                    { src = wc   + (u - 1966080u) * 8;   dst = w_bf + 3145728u + (u - 1966080u) * 8; }
  float4 v0 = ((const float4*)src)[0];
  float4 v1 = ((const float4*)src)[1];
  union { unsigned short us[8]; uint4 v; } o;
  o.us[0] = f2bf(v0.x); o.us[1] = f2bf(v0.y); o.us[2] = f2bf(v0.z); o.us[3] = f2bf(v0.w);
  o.us[4] = f2bf(v1.x); o.us[5] = f2bf(v1.y); o.us[6] = f2bf(v1.z); o.us[7] = f2bf(v1.w);
  *(uint4*)dst = o.v;
}

// ---------------------------------------------------------------------------
// Output projection: C[4096,1024] f32 = A x Wc^T + bc. 64x128 tile, BK=64,
// 4 waves as 2x2 of 32x64 (acc[2][4]), grid (64,8) = 512 blocks = 2/CU.
// Same XOR-swizzle staging relation as the proven 128x128 kernel.
__global__ __launch_bounds__(256, 2) void gemm_out(
    const unsigned short* __restrict__ A, const unsigned short* __restrict__ Bw,
    const float* __restrict__ bias, float* __restrict__ outp) {
  __shared__ __align__(16) unsigned short lA[64 * 64];
  __shared__ __align__(16) unsigned short lB[128 * 64];
  const int tid = threadIdx.x;
  const int lane = tid & 63;
  const int w = tid >> 6;
  const int wr = w >> 1, wcn = w & 1;
  const int tm = blockIdx.x * 64;
  const int tn = blockIdx.y * 128;

  const int srow = lane >> 3;
  const int scol = ((lane & 7) ^ srow) * 8;
  // wave w stages A rows 16w..16w+15 (2 gloads) and B rows 32w..32w+31 (4)
  const unsigned short* aptr = A + (size_t)(tm + 16 * w + srow) * 1024 + scol;
  const unsigned short* bptr = Bw + (size_t)(tn + 32 * w + srow) * 1024 + scol;
  unsigned short* lAw = &lA[(16 * w) * 64];
  unsigned short* lBw = &lB[(32 * w) * 64];

  const f32x4 zero = {0.f, 0.f, 0.f, 0.f};
  f32x4 acc[2][4];
#pragma unroll
  for (int i = 0; i < 2; ++i)
#pragma unroll
    for (int j = 0; j < 4; ++j) acc[i][j] = zero;

  for (int kb = 0; kb < 16; ++kb) {
    const int ko = kb * 64;
#pragma unroll
    for (int c = 0; c < 2; ++c)
      gload_lds16(aptr + ko + c * 8 * 1024, lAw + c * 8 * 64);
#pragma unroll
    for (int c = 0; c < 4; ++c)
      gload_lds16(bptr + ko + c * 8 * 1024, lBw + c * 8 * 64);
    __syncthreads();
#pragma unroll
    for (int kk = 0; kk < 2; ++kk) {
      short8 af[2], bfr[4];
#pragma unroll
      for (int mi = 0; mi < 2; ++mi) {
        int r = 32 * wr + 16 * mi + (lane & 15);
        int slot = (kk * 4 + (lane >> 4)) ^ (r & 7);
        af[mi] = *(const short8*)&lA[r * 64 + slot * 8];
      }
#pragma unroll
      for (int ni = 0; ni < 4; ++ni) {
        int r = 64 * wcn + 16 * ni + (lane & 15);
        int slot = (kk * 4 + (lane >> 4)) ^ (r & 7);
        bfr[ni] = *(const short8*)&lB[r * 64 + slot * 8];
      }
#pragma unroll
      for (int mi = 0; mi < 2; ++mi)
#pragma unroll
        for (int ni = 0; ni < 4; ++ni)
          acc[mi][ni] = __builtin_amdgcn_mfma_f32_16x16x32_bf16(
              af[mi], bfr[ni], acc[mi][ni], 0, 0, 0);
    }
    __syncthreads();
  }

  const int g4 = (lane >> 4) * 4;
  const int c0 = lane & 15;
#pragma unroll
  for (int mi = 0; mi < 2; ++mi) {
#pragma unroll
    for (int ni = 0; ni < 4; ++ni) {
      const int colt = tn + 64 * wcn + 16 * ni + c0;
      const float bv = bias[colt];
#pragma unroll
      for (int j = 0; j < 4; ++j) {
        const int rowt = tm + 32 * wr + 16 * mi + g4 + j;
        outp[(size_t)rowt * 1024 + colt] = acc[mi][ni][j] + bv;
      }
    }
  }
}

// ---------------------------------------------------------------------------
// Merged Q/K/V projection: one dispatch, grid (64, 24).
// y in [0,8): K  -> kh[b][n][j][d]                 (A = c_bf, M=8192)
// y in [8,16): V -> vt[b][n][d][pi(j)]             (A = c_bf, M=8192)
// y in [16,24): Q -> qh[b][n][i][d] * 0.125*log2e  (A = a_bf, M=4096; x<32)
// 1280 active blocks = 5/CU. Same proven tile structure.
__global__ __launch_bounds__(256, 2) void gemm_proj(
    const unsigned short* __restrict__ a_bf, const unsigned short* __restrict__ c_bf,
    const unsigned short* __restrict__ w_bf, const float* __restrict__ bq,
    const float* __restrict__ bk, const float* __restrict__ bv,
    unsigned short* __restrict__ qh, unsigned short* __restrict__ kh,
    unsigned short* __restrict__ vt) {
  const int yy = blockIdx.y;
  const int mode = yy >> 3;  // 0=K, 1=V, 2=Q
  if (mode == 2 && blockIdx.x >= 32) return;
  __shared__ __align__(16) unsigned short lA[128 * 64];
  __shared__ __align__(16) unsigned short lB[128 * 64];
  const int tid = threadIdx.x;
  const int lane = tid & 63;
  const int w = tid >> 6;
  const int wr = w >> 1, wcn = w & 1;
  const int tm = blockIdx.x * 128;
  const int tn = (yy & 7) * 128;
  const unsigned short* A  = (mode == 2) ? a_bf : c_bf;
  const unsigned short* Bw = (mode == 0) ? w_bf + (1u << 20)
                            : (mode == 1) ? w_bf + (2u << 20) : w_bf;
  const float* bias = (mode == 0) ? bk : (mode == 1) ? bv : bq;

  const int srow = lane >> 3;
  const int scol = ((lane & 7) ^ srow) * 8;
  const unsigned short* aptr = A + (size_t)(tm + 32 * w + srow) * 1024 + scol;
  const unsigned short* bptr = Bw + (size_t)(tn + 32 * w + srow) * 1024 + scol;
  unsigned short* lAw = &lA[(32 * w) * 64];
  unsigned short* lBw = &lB[(32 * w) * 64];

  const f32x4 zero = {0.f, 0.f, 0.f, 0.f};
  f32x4 acc[4][4];
#pragma unroll
  for (int i = 0; i < 4; ++i)
#pragma unroll
    for (int j = 0; j < 4; ++j) acc[i][j] = zero;

  for (int kb = 0; kb < 16; ++kb) {
    const int ko = kb * 64;
#pragma unroll
    for (int c = 0; c < 4; ++c) {
      gload_lds16(aptr + ko + c * 8 * 1024, lAw + c * 8 * 64);
      gload_lds16(bptr + ko + c * 8 * 1024, lBw + c * 8 * 64);
    }
    __syncthreads();
#pragma unroll
    for (int kk = 0; kk < 2; ++kk) {
      short8 af[4], bfr[4];
#pragma unroll
      for (int mi = 0; mi < 4; ++mi) {
        int r = 64 * wr + 16 * mi + (lane & 15);
        int slot = (kk * 4 + (lane >> 4)) ^ (r & 7);
        af[mi] = *(const short8*)&lA[r * 64 + slot * 8];
      }
#pragma unroll
      for (int ni = 0; ni < 4; ++ni) {
        int r = 64 * wcn + 16 * ni + (lane & 15);
        int slot = (kk * 4 + (lane >> 4)) ^ (r & 7);
        bfr[ni] = *(const short8*)&lB[r * 64 + slot * 8];
      }
#pragma unroll
      for (int mi = 0; mi < 4; ++mi)
#pragma unroll
        for (int ni = 0; ni < 4; ++ni)
          acc[mi][ni] = __builtin_amdgcn_mfma_f32_16x16x32_bf16(
              af[mi], bfr[ni], acc[mi][ni], 0, 0, 0);
    }
    __syncthreads();
  }

  const int g4 = (lane >> 4) * 4;
  const int c0 = lane & 15;
#pragma unroll
  for (int mi = 0; mi < 4; ++mi) {
#pragma unroll
    for (int ni = 0; ni < 4; ++ni) {
      const int colt = tn + 64 * wcn + 16 * ni + c0;
      const float bvv = bias[colt];
#pragma unroll
      for (int j = 0; j < 4; ++j) {
        const int rowt = tm + 64 * wr + 16 * mi + g4 + j;
        const float v = acc[mi][ni][j] + bvv;
        const int jj = rowt >> 1, b = rowt & 1, n = colt >> 6, d = colt & 63;
        if (mode == 0) {
          kh[(((size_t)(b * 16 + n) * 4096 + jj) << 6) + d] = f2bf(v);
        } else if (mode == 1) {
          const int j6 = jj & 63;
          const int pos = (j6 & 3) | (((j6 >> 4) & 1) << 2) | (((j6 >> 2) & 3) << 3) |
                          (((j6 >> 5) & 1) << 5);
          vt[((size_t)(b * 16 + n) * 64 + d) * 4096 + (jj & ~63) + pos] = f2bf(v);
        } else {
          qh[(((size_t)(b * 16 + n) * 2048 + jj) << 6) + d] =
              f2bf(v * 0.1803368801111f);  // 1/8 * log2(e): exp2-direct scores
        }
      }
    }
  }
}

// ---------------------------------------------------------------------------
// Flash attention (round-10 proven). Block = (head, 128-row q-tile):
// 256 threads / 4 waves, 32 q-rows per wave (mi=0,1). Grid 512 = 2 blocks/CU.
// Pair-pipelined: qkt(0); qkt(1); sm(0); pv(0); sm(1); pv(1).
// Defer-max softmax; l as per-lane partials (tree), epilogue reduce.
// V pre-permuted so PV B-frag is one ds_read_b128. XCD map: f&7 = xcd.
__global__ __launch_bounds__(256, 2) void attn_kernel(
    const unsigned short* __restrict__ qh, const unsigned short* __restrict__ kh,
    const unsigned short* __restrict__ vt, unsigned short* __restrict__ vec) {
  __shared__ __align__(16) unsigned short kl[2][2][64 * 64];
  __shared__ __align__(16) unsigned short vl[2][2][64 * 64];
  const int tid = threadIdx.x;
  const int lane = tid & 63;
  const int w = tid >> 6;  // 0..3
  const int g = lane >> 4;
  const int l4 = lane & 15;
  const int f = blockIdx.x;
  const int head = (f & 7) * 4 + ((f >> 3) & 3);
  const int qt = f >> 5;  // 0..15
  const int b = head >> 4, n = head & 15;
  const unsigned short* qbase = qh + ((size_t)head * 2048 + qt * 128 + 32 * w) * 64;
  const unsigned short* kbase = kh + (size_t)head * 4096 * 64;
  const unsigned short* vbase = vt + (size_t)head * 64 * 4096;

  short8 qf[2][2];
#pragma unroll
  for (int mi = 0; mi < 2; ++mi)
#pragma unroll
    for (int kk = 0; kk < 2; ++kk)
      qf[mi][kk] = *(const short8*)&qbase[(16 * mi + l4) * 64 + kk * 32 + g * 8];

  const f32x4 zero = {0.f, 0.f, 0.f, 0.f};
  f32x4 oacc[2][4];
#pragma unroll
  for (int mi = 0; mi < 2; ++mi)
#pragma unroll
    for (int nd = 0; nd < 4; ++nd) oacc[mi][nd] = zero;
  float mrow[2] = {-3.0e38f, -3.0e38f};
  float lsum[2] = {0.f, 0.f};

  const int srow = lane >> 3;
  const int scol = ((lane & 7) ^ srow) * 8;
  const unsigned short* kp = kbase + (size_t)(16 * w + srow) * 64 + scol;
  const unsigned short* vp = vbase + (size_t)(16 * w + srow) * 4096 + scol;

  auto stage_pair = [&](int jp, int bufi) {
#pragma unroll
    for (int sub = 0; sub < 2; ++sub) {
      gload_lds16(kp + (size_t)jp * 8192 + sub * 4096,
                  &kl[bufi][sub][(16 * w) * 64]);
      gload_lds16(kp + (size_t)jp * 8192 + sub * 4096 + 8 * 64,
                  &kl[bufi][sub][(16 * w + 8) * 64]);
      gload_lds16(vp + jp * 128 + sub * 64, &vl[bufi][sub][(16 * w) * 64]);
      gload_lds16(vp + jp * 128 + sub * 64 + 8 * 4096,
                  &vl[bufi][sub][(16 * w + 8) * 64]);
    }
  };

  auto qkt = [&](const unsigned short* kbuf, f32x4 (&s)[2][4]) {
#pragma unroll
    for (int mi = 0; mi < 2; ++mi)
#pragma unroll
      for (int nj = 0; nj < 4; ++nj) s[mi][nj] = zero;
    __builtin_amdgcn_s_setprio(1);
#pragma unroll
    for (int kk = 0; kk < 2; ++kk) {
      short8 bk[4];
#pragma unroll
      for (int nj = 0; nj < 4; ++nj) {
        int r = 16 * nj + l4;
        int slot = (kk * 4 + g) ^ (r & 7);
        bk[nj] = *(const short8*)&kbuf[r * 64 + slot * 8];
      }
#pragma unroll
      for (int mi = 0; mi < 2; ++mi)
#pragma unroll
        for (int nj = 0; nj < 4; ++nj)
          s[mi][nj] = __builtin_amdgcn_mfma_f32_16x16x32_bf16(bk[nj], qf[mi][kk], s[mi][nj], 0, 0, 0);
    }
    __builtin_amdgcn_s_setprio(0);
  };

  auto sm = [&](f32x4 (&s)[2][4], short8 (&pa)[2][2]) {
    float pm[2];
#pragma unroll
    for (int mi = 0; mi < 2; ++mi) {
      float t0 = max3f(s[mi][0][0], s[mi][0][1], s[mi][0][2]);
      float t1 = max3f(s[mi][0][3], s[mi][1][0], s[mi][1][1]);
      float t2 = max3f(s[mi][1][2], s[mi][1][3], s[mi][2][0]);
      float t3 = max3f(s[mi][2][1], s[mi][2][2], s[mi][2][3]);
      float t4 = max3f(s[mi][3][0], s[mi][3][1], s[mi][3][2]);
      float p5 = max3f(t0, t1, t2);
      p5 = max3f(p5, t3, t4);
      pm[mi] = fmaxf(p5, s[mi][3][3]);
    }
    float pj = fmaxf(pm[0], pm[1]);
    pj = fmaxf(pj, __shfl_xor(pj, 16));
    pj = fmaxf(pj, __shfl_xor(pj, 32));
    if (!__all(pj <= fminf(mrow[0], mrow[1]) + 8.f)) {
#pragma unroll
      for (int mi = 0; mi < 2; ++mi) {
        const float mnew = fmaxf(mrow[mi], pj);
        const float sc = __builtin_amdgcn_exp2f(mrow[mi] - mnew);
        mrow[mi] = mnew;
        lsum[mi] *= sc;
#pragma unroll
        for (int reg = 0; reg < 4; ++reg) {
          const float scr = __shfl(sc, 4 * g + reg);
#pragma unroll
          for (int nd = 0; nd < 4; ++nd) oacc[mi][nd][reg] *= scr;
        }
      }
    }
#pragma unroll
    for (int mi = 0; mi < 2; ++mi) {
      const float m = mrow[mi];
      float tr[4];
#pragma unroll
      for (int nj = 0; nj < 4; ++nj) {
        const float p0 = __builtin_amdgcn_exp2f(s[mi][nj][0] - m);
        const float p1 = __builtin_amdgcn_exp2f(s[mi][nj][1] - m);
        const float p2 = __builtin_amdgcn_exp2f(s[mi][nj][2] - m);
        const float p3 = __builtin_amdgcn_exp2f(s[mi][nj][3] - m);
        s[mi][nj][0] = p0; s[mi][nj][1] = p1; s[mi][nj][2] = p2; s[mi][nj][3] = p3;
        tr[nj] = (p0 + p1) + (p2 + p3);
      }
      lsum[mi] += (tr[0] + tr[1]) + (tr[2] + tr[3]);
#pragma unroll
      for (int kk2 = 0; kk2 < 2; ++kk2) {
        union { unsigned int u[4]; short8 v; } t;
#pragma unroll
        for (int wd = 0; wd < 4; ++wd) {
          const int nj = (wd >> 1) + 2 * kk2;
          const int r0 = (wd & 1) * 2;
          t.u[wd] = cvtpk(s[mi][nj][r0], s[mi][nj][r0 + 1]);
        }
        pa[mi][kk2] = t.v;
      }
    }
  };

  auto pv = [&](const short8 (&pa)[2][2], const unsigned short* vbuf) {
    __builtin_amdgcn_s_setprio(1);
#pragma unroll
    for (int kk2 = 0; kk2 < 2; ++kk2) {
      short8 bv4[4];
#pragma unroll
      for (int nd = 0; nd < 4; ++nd) {
        const int r = 16 * nd + l4;
        const int blk = (g + 4 * kk2) ^ (r & 7);
        bv4[nd] = *(const short8*)&vbuf[r * 64 + blk * 8];
      }
#pragma unroll
      for (int mi = 0; mi < 2; ++mi)
#pragma unroll
        for (int nd = 0; nd < 4; ++nd)
          oacc[mi][nd] = __builtin_amdgcn_mfma_f32_16x16x32_bf16(pa[mi][kk2], bv4[nd], oacc[mi][nd], 0, 0, 0);
    }
    __builtin_amdgcn_s_setprio(0);
  };

  f32x4 sA[2][4], sB[2][4];
  short8 paA[2][2], paB[2][2];
  auto pair = [&](int bufi) {
    qkt(kl[bufi][0], sA);
    qkt(kl[bufi][1], sB);
    sm(sA, paA);
    pv(paA, vl[bufi][0]);
    sm(sB, paB);
    pv(paB, vl[bufi][1]);
  };

  stage_pair(0, 0);
  asm volatile("s_waitcnt vmcnt(0)" ::: "memory");
  BARRIER_RAW();

  for (int t2 = 0; t2 < 16; ++t2) {
    stage_pair(2 * t2 + 1, 1);
    pair(0);
    asm volatile("s_waitcnt vmcnt(0)" ::: "memory");
    BARRIER_RAW();
    if (t2 < 15) stage_pair(2 * t2 + 2, 0);
    pair(1);
    if (t2 < 15) {
      asm volatile("s_waitcnt vmcnt(0)" ::: "memory");
      BARRIER_RAW();
    }
  }

#pragma unroll
  for (int mi = 0; mi < 2; ++mi) {
    float l = lsum[mi];
    l += __shfl_xor(l, 16);
    l += __shfl_xor(l, 32);
#pragma unroll
    for (int reg = 0; reg < 4; ++reg) {
      const float lr = __shfl(l, 4 * g + reg);
      const float inv = 1.f / lr;
      const int i = qt * 128 + 32 * w + 16 * mi + 4 * g + reg;
#pragma unroll
      for (int nd = 0; nd < 4; ++nd) {
        const int d = 16 * nd + l4;
        vec[(size_t)(i * 2 + b) * 1024 + n * 64 + d] = f2bf(oacc[mi][nd][reg] * inv);
      }
    }
  }
}

// ---------------------------------------------------------------------------
extern "C" void kernel_launch(void* const* d_in, const int* in_sizes, int n_in,
                              void* d_out, int out_size, void* d_ws, size_t ws_size,
                              hipStream_t stream) {
  (void)in_sizes; (void)n_in; (void)out_size; (void)ws_size;
  const float* q    = (const float*)d_in[0];
  const float* kv   = (const float*)d_in[1];
  const float* mem_ = (const float*)d_in[2];
  const float* wq   = (const float*)d_in[3];
  const float* bq   = (const float*)d_in[4];
  const float* wk   = (const float*)d_in[5];
  const float* bk   = (const float*)d_in[6];
  const float* wv   = (const float*)d_in[7];
  const float* bv   = (const float*)d_in[8];
  const float* wc   = (const float*)d_in[9];
  const float* bc   = (const float*)d_in[10];

  char* ws = (char*)d_ws;
  unsigned short* w_bf = (unsigned short*)(ws);                       // 8 MB: wq,wk,wv,wc
  unsigned short* a_bf = (unsigned short*)(ws + (8ull << 20));        // 8 MB: q bf16 [4096][1024]
  unsigned short* c_bf = (unsigned short*)(ws + (16ull << 20));       // 16 MB: concat(mem,kv)
  unsigned short* qhb  = (unsigned short*)(ws + (32ull << 20));       // 8 MB: [b][n][2048][64]
  unsigned short* khb  = (unsigned short*)(ws + (40ull << 20));       // 16 MB: [b][n][4096][64]
  unsigned short* vtb  = (unsigned short*)(ws + (56ull << 20));       // 16 MB: [b][n][64][pi(j)]
  unsigned short* vecb = a_bf;  // reuse (a_bf dead after Q projection)

  convert_all<<<8192, 256, 0, stream>>>(q, mem_, kv, wq, wk, wv, wc, a_bf, c_bf, w_bf);
  gemm_proj<<<dim3(64, 24), 256, 0, stream>>>(a_bf, c_bf, w_bf, bq, bk, bv,
                                              qhb, khb, vtb);
  attn_kernel<<<512, 256, 0, stream>>>(qhb, khb, vtb, vecb);
  gemm_out<<<dim3(64, 8), 256, 0, stream>>>(vecb, w_bf + (3u << 20), bc, (float*)d_out);
}